// Round 15
// baseline (295.996 us; speedup 1.0000x reference)
//
#include <hip/hip_runtime.h>

// GNN: 3x (GraphConv -> BatchNorm -> ReLU) -> global_mean_pool -> Linear.
// bf16 MFMA pipeline: features bf16, mfma_f32_16x16x32_bf16, fp32 acc/stats.
//
// r14: aggregate FUSED into the gemm (per-block gather -> LDS A-tile,
// wave-local so no extra barriers); CSR build collapsed to coarse_scatter +
// bukScan + bucket_finalize (count+local-scan+scatter in one kernel).
// r13's column-slicing REVERTED: FETCH showed 100% L2 miss regardless
// (block->XCD mapping not round-robin) and it cost csr re-streaming.
//
// History: r1 CSR vs 1.3ms scatter atomics; r5 global_load_lds divergent-src
// 65x HBM amp; r4-r8 fp32 FMA plateau (LDS-feed wall) -> r9 bf16 MFMA (363);
// r10 XCD-local 2-level sort (322); r11 barrier-free gemm K-loop (314);
// r12 stats-atomic 32-slot spread + fusions (260). Gather traffic ~103MB/layer
// at ~2.9TB/s is the structural floor of this op.

constexpr int   NN   = 50000;
constexpr int   NE   = 800000;
constexpr int   DH   = 128;
constexpr int   NC   = 10;
constexpr int   NG   = 1024;
constexpr float EPSV = 1e-5f;
constexpr int   NBUK = (NN + 255) / 256;    // 196 coarse buckets (dst>>8)
constexpr int   BCAP = 5120;                // slots per bucket (avg 4081, 16 sigma)
constexpr int   EPB  = 8192;                // edges per coarse block
constexpr int   CSB  = (NE + EPB - 1) / EPB; // 98 coarse blocks
constexpr int   NSLOT= 32;                  // stats atomic spread factor

typedef __attribute__((ext_vector_type(8))) short bf16x8;
typedef __attribute__((ext_vector_type(4))) float f32x4;

__device__ __forceinline__ float bflo(unsigned u) { return __uint_as_float(u << 16); }
__device__ __forceinline__ float bfhi(unsigned u) { return __uint_as_float(u & 0xffff0000u); }
__device__ __forceinline__ unsigned short f2bf(float f) {
    unsigned u = __float_as_uint(f);
    return (unsigned short)((u + 0x7fffu + ((u >> 16) & 1u)) >> 16);
}
__device__ __forceinline__ unsigned pk2(float a, float b) {
    return (unsigned)f2bf(a) | ((unsigned)f2bf(b) << 16);
}

// ------------------------------------------------- CSR build (2-level sort) ---
__global__ __launch_bounds__(256) void coarse_scatter_kernel(
    const int* __restrict__ src, const int* __restrict__ dst,
    int* __restrict__ bukCnt, int2* __restrict__ pairs)
{
    __shared__ int cnt[NBUK], base[NBUK], cur[NBUK];
    const int tid = threadIdx.x;
    const int e0 = blockIdx.x * EPB;
    const int n  = min(EPB, NE - e0);

    for (int b = tid; b < NBUK; b += 256) cnt[b] = 0;
    __syncthreads();
    for (int i = tid; i < n; i += 256)
        atomicAdd(&cnt[dst[e0 + i] >> 8], 1);
    __syncthreads();
    for (int b = tid; b < NBUK; b += 256) {
        base[b] = (cnt[b] > 0) ? atomicAdd(&bukCnt[b], cnt[b]) : 0;
        cur[b] = 0;
    }
    __syncthreads();
    for (int i = tid; i < n; i += 256) {
        int d = dst[e0 + i], s = src[e0 + i];
        int b = d >> 8;
        int r = atomicAdd(&cur[b], 1);
        int p = base[b] + r;
        if (p >= BCAP) p = BCAP - 1;
        pairs[(size_t)b * BCAP + p] = make_int2(s, d);
    }
}

// exclusive scan of bukCnt[196] -> bukBase
__global__ __launch_bounds__(256) void bukscan_kernel(
    const int* __restrict__ bukCnt, int* __restrict__ bukBase)
{
    __shared__ int tmp[256];
    int t = threadIdx.x;
    int v = (t < NBUK) ? bukCnt[t] : 0;
    tmp[t] = v;
    __syncthreads();
    for (int off = 1; off < 256; off <<= 1) {
        int u = (t >= off) ? tmp[t - off] : 0;
        __syncthreads();
        tmp[t] += u;
        __syncthreads();
    }
    if (t < NBUK) bukBase[t] = tmp[t] - v;   // exclusive
}

// Per-bucket: degree count -> local prefix -> offsets -> fine scatter.
// Bucket b owns nodes [b*256, b*256+256) and csr region [bukBase[b], +cnt).
__global__ __launch_bounds__(256) void bucket_finalize_kernel(
    const int2* __restrict__ pairs, const int* __restrict__ bukCnt,
    const int* __restrict__ bukBase, int* __restrict__ offsets,
    int* __restrict__ csr_src)
{
    __shared__ int cnt[256], tmp[256], pos[256];
    const int b = blockIdx.x;
    const int tid = threadIdx.x;
    cnt[tid] = 0;
    __syncthreads();
    const int n = min(bukCnt[b], BCAP);
    const int2* p = pairs + (size_t)b * BCAP;
    for (int i = tid; i < n; i += 256)
        atomicAdd(&cnt[p[i].y & 255], 1);
    __syncthreads();
    int d = cnt[tid];
    tmp[tid] = d;
    __syncthreads();
    for (int off = 1; off < 256; off <<= 1) {
        int u = (tid >= off) ? tmp[tid - off] : 0;
        __syncthreads();
        tmp[tid] += u;
        __syncthreads();
    }
    const int base = bukBase[b];
    int o = base + tmp[tid] - d;     // exclusive local prefix + bucket base
    pos[tid] = o;
    int node = b * 256 + tid;
    if (node < NN) offsets[node] = o;
    if (b == NBUK - 1 && tid == 0) offsets[NN] = NE;
    __syncthreads();
    for (int i = tid; i < n; i += 256) {
        int2 e = p[i];
        int r = atomicAdd(&pos[e.y & 255], 1);
        csr_src[r] = e.x;
    }
}

// ------------------------------------------------------------------- goff ---
__global__ __launch_bounds__(256) void goff_kernel(
    const int* __restrict__ batch, int* __restrict__ goff)
{
    int g = blockIdx.x * 256 + threadIdx.x;
    if (g > NG) return;
    int lo = 0, hi = NN;
    while (lo < hi) {
        int mid = (lo + hi) >> 1;
        if (batch[mid] < g) lo = mid + 1; else hi = mid;
    }
    goff[g] = lo;
}

// ------------------------------------------------------------ conversions ---
__global__ __launch_bounds__(256) void convert_x_kernel(
    const float* __restrict__ x, unsigned short* __restrict__ xb)
{
    int i = blockIdx.x * 256 + threadIdx.x;   // elem8 index
    if (i >= NN * DH / 8) return;
    const float4* p = reinterpret_cast<const float4*>(x + (size_t)i * 8);
    float4 v0 = p[0], v1 = p[1];
    uint4 o;
    o.x = pk2(v0.x, v0.y); o.y = pk2(v0.z, v0.w);
    o.z = pk2(v1.x, v1.y); o.w = pk2(v1.z, v1.w);
    *reinterpret_cast<uint4*>(xb + (size_t)i * 8) = o;
}

__global__ __launch_bounds__(256) void transpose_w_kernel(
    const float* __restrict__ w0, const float* __restrict__ w1,
    const float* __restrict__ w2, const float* __restrict__ w3,
    const float* __restrict__ w4, const float* __restrict__ w5,
    unsigned short* __restrict__ t0, unsigned short* __restrict__ t1,
    unsigned short* __restrict__ t2, unsigned short* __restrict__ t3,
    unsigned short* __restrict__ t4, unsigned short* __restrict__ t5)
{
    const float* srcs[6] = {w0, w1, w2, w3, w4, w5};
    unsigned short* dsts[6] = {t0, t1, t2, t3, t4, t5};
    int m = blockIdx.x >> 4;
    int sub = blockIdx.x & 15;
    const float* s = srcs[m];
    unsigned short* d = dsts[m];
    for (int it = 0; it < 4; ++it) {
        int i = sub * 1024 + it * 256 + threadIdx.x;   // 0..16383
        int c = i & 127, k = i >> 7;
        d[c * 128 + k] = f2bf(s[k * 128 + c]);         // coalesced read
    }
}

// ------------------------------------------------------------ fused layer ---
// OUT = t(X) @ Wr + agg(t(X)) @ Wl + bias, agg gathered IN-KERNEL.
// 64 nodes/block, 4 waves x 16 nodes. W^T staged one matrix at a time
// (34.8 KB). Each wave gathers its own 16 nodes' neighbor sums into the
// LDS A-tile (wave-local: no barrier needed before its own phase-2 reads).
// Stats -> slot blockIdx&31 (r12: L2 atomic serialization fix).
template <bool TRANSFORM>
__global__ __launch_bounds__(256) void layer_kernel(
    const unsigned short* __restrict__ Xb,
    const unsigned short* __restrict__ Wrt, const unsigned short* __restrict__ Wlt,
    const float* __restrict__ bias, const float* __restrict__ scIn,
    const float* __restrict__ shIn, const int* __restrict__ offsets,
    const int* __restrict__ csr_src, unsigned short* __restrict__ OUTb,
    float* __restrict__ stats)
{
    __shared__ unsigned short sW[128][136];    // 34.8 KB, Wr then Wl
    __shared__ unsigned short sAgg[64][136];   // 17.4 KB bf16 A-tile
    __shared__ float sScale[DH], sShift[DH];

    const int tid  = threadIdx.x;
    const int lane = tid & 63;
    const int wave = tid >> 6;
    const int row0 = blockIdx.x * 64;
    const int wrow = wave * 16;
    const int l15  = lane & 15;
    const int lk   = (lane >> 4) * 8;    // k sub-offset for A/B frags

    if (TRANSFORM && tid < DH) {
        sScale[tid] = scIn[tid];
        sShift[tid] = shIn[tid];
    }
    // stage Wr^T
#pragma unroll
    for (int i = 0; i < 8; ++i) {
        int f = i * 256 + tid;
        int c = f >> 4;
        int ks = (f & 15) * 8;
        *reinterpret_cast<uint4*>(&sW[c][ks]) =
            *reinterpret_cast<const uint4*>(Wrt + c * 128 + ks);
    }

    f32x4 acc[8];
#pragma unroll
    for (int nt = 0; nt < 8; ++nt) acc[nt] = (f32x4){0.f, 0.f, 0.f, 0.f};

    const int arow = row0 + wrow + l15;
    const bool valid = arow < NN;
    const unsigned short* xptr = Xb + (size_t)arow * DH + lk;

    uint4 pre[4];
#pragma unroll
    for (int t = 0; t < 4; ++t)
        pre[t] = valid ? *reinterpret_cast<const uint4*>(xptr + t * 32)
                       : make_uint4(0u, 0u, 0u, 0u);

    __syncthreads();   // Wr ready (+ sScale/sShift)

    // ---- phase 1: t(X) @ Wr
#pragma unroll
    for (int t = 0; t < 4; ++t) {
        uint4 v = pre[t];
        if (TRANSFORM) {
            int cb = t * 32 + lk;
            float f[8] = {bflo(v.x), bfhi(v.x), bflo(v.y), bfhi(v.y),
                          bflo(v.z), bfhi(v.z), bflo(v.w), bfhi(v.w)};
#pragma unroll
            for (int j = 0; j < 8; ++j)
                f[j] = fmaxf(fmaf(f[j], sScale[cb + j], sShift[cb + j]), 0.f);
            v.x = pk2(f[0], f[1]); v.y = pk2(f[2], f[3]);
            v.z = pk2(f[4], f[5]); v.w = pk2(f[6], f[7]);
        }
        bf16x8 a = *reinterpret_cast<bf16x8*>(&v);
        const int kb = t * 32;
#pragma unroll
        for (int nt = 0; nt < 8; ++nt) {
            bf16x8 b = *reinterpret_cast<const bf16x8*>(&sW[nt * 16 + l15][kb + lk]);
            acc[nt] = __builtin_amdgcn_mfma_f32_16x16x32_bf16(a, b, acc[nt], 0, 0, 0);
        }
    }

    // ---- gather: this wave's 16 nodes -> sAgg rows [wrow, wrow+16)
    {
        const int gl  = lane & 15;          // col group 0..15
        const int c8  = gl * 8;
        float scv[8], shv[8];
        if (TRANSFORM) {
#pragma unroll
            for (int j = 0; j < 8; ++j) { scv[j] = sScale[c8 + j]; shv[j] = sShift[c8 + j]; }
        }
#pragma unroll
        for (int sub = 0; sub < 4; ++sub) {
            int nloc = wrow + sub * 4 + (lane >> 4);   // local row 0..63
            int node = row0 + nloc;
            float ac[8] = {0.f,0.f,0.f,0.f,0.f,0.f,0.f,0.f};
            if (node < NN) {
                auto addv = [&](uint4 v) {
                    float f[8] = {bflo(v.x), bfhi(v.x), bflo(v.y), bfhi(v.y),
                                  bflo(v.z), bfhi(v.z), bflo(v.w), bfhi(v.w)};
#pragma unroll
                    for (int j = 0; j < 8; ++j) {
                        float t = TRANSFORM ? fmaxf(fmaf(f[j], scv[j], shv[j]), 0.f) : f[j];
                        ac[j] += t;
                    }
                };
                int beg = offsets[node], end = offsets[node + 1];
                int e = beg;
                for (; e + 3 < end; e += 4) {
                    int s0 = csr_src[e],     s1 = csr_src[e + 1];
                    int s2 = csr_src[e + 2], s3 = csr_src[e + 3];
                    uint4 v0 = *reinterpret_cast<const uint4*>(Xb + (size_t)s0 * DH + c8);
                    uint4 v1 = *reinterpret_cast<const uint4*>(Xb + (size_t)s1 * DH + c8);
                    uint4 v2 = *reinterpret_cast<const uint4*>(Xb + (size_t)s2 * DH + c8);
                    uint4 v3 = *reinterpret_cast<const uint4*>(Xb + (size_t)s3 * DH + c8);
                    addv(v0); addv(v1); addv(v2); addv(v3);
                }
                for (; e < end; ++e)
                    addv(*reinterpret_cast<const uint4*>(Xb + (size_t)csr_src[e] * DH + c8));
            }
            uint4 o;
            o.x = pk2(ac[0], ac[1]); o.y = pk2(ac[2], ac[3]);
            o.z = pk2(ac[4], ac[5]); o.w = pk2(ac[6], ac[7]);
            *reinterpret_cast<uint4*>(&sAgg[nloc][c8]) = o;
        }
    }

    __syncthreads();   // all waves done with Wr (and sAgg complete)
    // stage Wl^T
#pragma unroll
    for (int i = 0; i < 8; ++i) {
        int f = i * 256 + tid;
        int c = f >> 4;
        int ks = (f & 15) * 8;
        *reinterpret_cast<uint4*>(&sW[c][ks]) =
            *reinterpret_cast<const uint4*>(Wlt + c * 128 + ks);
    }
    __syncthreads();   // Wl ready

    // ---- phase 2: agg @ Wl (A-frags from LDS)
#pragma unroll
    for (int t = 0; t < 4; ++t) {
        bf16x8 a = *reinterpret_cast<const bf16x8*>(&sAgg[wrow + l15][t * 32 + lk]);
        const int kb = t * 32;
#pragma unroll
        for (int nt = 0; nt < 8; ++nt) {
            bf16x8 b = *reinterpret_cast<const bf16x8*>(&sW[nt * 16 + l15][kb + lk]);
            acc[nt] = __builtin_amdgcn_mfma_f32_16x16x32_bf16(a, b, acc[nt], 0, 0, 0);
        }
    }

    // ---- epilogue: bias, bf16 store, fp32 column stats
    float s_[8] = {0,0,0,0,0,0,0,0}, q_[8] = {0,0,0,0,0,0,0,0};
#pragma unroll
    for (int nt = 0; nt < 8; ++nt) {
        float bvn = bias[nt * 16 + l15];
#pragma unroll
        for (int r = 0; r < 4; ++r) {
            int orow = row0 + wrow + ((lane >> 4) << 2) + r;
            float o = acc[nt][r] + bvn;
            if (orow < NN) {
                OUTb[(size_t)orow * DH + nt * 16 + l15] = f2bf(o);
                s_[nt] += o;
                q_[nt] += o * o;
            }
        }
    }
#pragma unroll
    for (int nt = 0; nt < 8; ++nt) {
        s_[nt] += __shfl_xor(s_[nt], 16, 64);
        s_[nt] += __shfl_xor(s_[nt], 32, 64);
        q_[nt] += __shfl_xor(q_[nt], 16, 64);
        q_[nt] += __shfl_xor(q_[nt], 32, 64);
    }
    __syncthreads();                     // sAgg dead -> reuse as scratch
    float* ldsS = reinterpret_cast<float*>(&sAgg[0][0]);   // [4][128]
    float* ldsQ = ldsS + 512;                              // [4][128]
    if (lane < 16) {
#pragma unroll
        for (int nt = 0; nt < 8; ++nt) {
            ldsS[wave * DH + nt * 16 + l15] = s_[nt];
            ldsQ[wave * DH + nt * 16 + l15] = q_[nt];
        }
    }
    __syncthreads();
    if (tid < DH) {
        float s = ldsS[tid] + ldsS[DH + tid] + ldsS[2 * DH + tid] + ldsS[3 * DH + tid];
        float q = ldsQ[tid] + ldsQ[DH + tid] + ldsQ[2 * DH + tid] + ldsQ[3 * DH + tid];
        float* slot = stats + (size_t)(blockIdx.x & (NSLOT - 1)) * 256;
        atomicAdd(&slot[tid], s);
        atomicAdd(&slot[128 + tid], q);
    }
}

// --------------------------------------------------------------- finalize ---
__global__ __launch_bounds__(128) void finalize_kernel(
    const float* __restrict__ stats, const float* __restrict__ gamma,
    const float* __restrict__ beta, float* __restrict__ sc,
    float* __restrict__ sh)
{
    int j = threadIdx.x;
    float s = 0.f, q = 0.f;
#pragma unroll 8
    for (int sl = 0; sl < NSLOT; ++sl) {
        s += stats[sl * 256 + j];
        q += stats[sl * 256 + 128 + j];
    }
    float mean = s * (1.f / NN);
    float var  = q * (1.f / NN) - mean * mean;
    float sf = rsqrtf(var + EPSV) * gamma[j];
    sc[j] = sf;
    sh[j] = beta[j] - mean * sf;
}

// ---------------------------------------------------------- pool+classify ---
__global__ __launch_bounds__(128) void pool_classify_kernel(
    const unsigned short* __restrict__ Hb, const int* __restrict__ goff,
    const float* __restrict__ sc, const float* __restrict__ sh,
    const float* __restrict__ wcls, const float* __restrict__ bcls,
    float* __restrict__ out)
{
    __shared__ float pl[DH];
    int g = blockIdx.x;
    int j = threadIdx.x;
    int beg = goff[g], end = goff[g + 1];
    float s = 0.f;
    for (int n = beg; n < end; ++n)
        s += bflo((unsigned)Hb[(size_t)n * DH + j]);
    float cnt = (float)(end - beg);
    pl[j] = (s * sc[j] + cnt * sh[j]) / fmaxf(cnt, 1.f);
    __syncthreads();
    if (j < NC) {
        float v = bcls[j];
#pragma unroll 16
        for (int k = 0; k < DH; ++k) v += pl[k] * wcls[k * NC + j];
        out[(size_t)g * NC + j] = v;
    }
}

// ----------------------------------------------------------------- launch ---
extern "C" void kernel_launch(void* const* d_in, const int* in_sizes, int n_in,
                              void* d_out, int out_size, void* d_ws, size_t ws_size,
                              hipStream_t stream)
{
    const float* x    = (const float*)d_in[0];
    const int*   ei   = (const int*)d_in[1];
    const int*   batch= (const int*)d_in[2];
    const float* wr1  = (const float*)d_in[3];
    const float* wl1  = (const float*)d_in[4];
    const float* b1   = (const float*)d_in[5];
    const float* wr2  = (const float*)d_in[6];
    const float* wl2  = (const float*)d_in[7];
    const float* b2   = (const float*)d_in[8];
    const float* wr3  = (const float*)d_in[9];
    const float* wl3  = (const float*)d_in[10];
    const float* b3   = (const float*)d_in[11];
    const float* g1   = (const float*)d_in[12];
    const float* be1  = (const float*)d_in[13];
    const float* g2   = (const float*)d_in[14];
    const float* be2  = (const float*)d_in[15];
    const float* g3   = (const float*)d_in[16];
    const float* be3  = (const float*)d_in[17];
    const float* wcls = (const float*)d_in[18];
    const float* bcls = (const float*)d_in[19];
    float* out = (float*)d_out;

    const int* srcp = ei;
    const int* dstp = ei + NE;

    char* ws = (char*)d_ws;
    const size_t featB16 = (size_t)NN * DH * sizeof(unsigned short);   // 12.8 MB
    size_t off = 0;
    auto alloc = [&](size_t bytes) {
        void* p = ws + off;
        off += (bytes + 255) & ~(size_t)255;
        return p;
    };
    unsigned short* xb    = (unsigned short*)alloc(featB16);
    unsigned short* hAb   = (unsigned short*)alloc(featB16);
    unsigned short* hBb   = (unsigned short*)alloc(featB16);
    unsigned short* wrt1  = (unsigned short*)alloc(DH * DH * 2);
    unsigned short* wlt1  = (unsigned short*)alloc(DH * DH * 2);
    unsigned short* wrt2  = (unsigned short*)alloc(DH * DH * 2);
    unsigned short* wlt2  = (unsigned short*)alloc(DH * DH * 2);
    unsigned short* wrt3  = (unsigned short*)alloc(DH * DH * 2);
    unsigned short* wlt3  = (unsigned short*)alloc(DH * DH * 2);
    float* statsAll = (float*)alloc(3 * NSLOT * 256 * sizeof(float));  // 96 KB
    float* stats1 = statsAll;
    float* stats2 = statsAll + NSLOT * 256;
    float* stats3 = statsAll + 2 * NSLOT * 256;
    int*   offsets = (int*)alloc((NN + 1) * sizeof(int));
    int*   csr_src = (int*)alloc(NE * sizeof(int));
    int2*  pairs   = (int2*)alloc((size_t)NBUK * BCAP * sizeof(int2));  // 8 MB
    int*   bukCnt  = (int*)alloc(NBUK * sizeof(int));
    int*   bukBase = (int*)alloc(NBUK * sizeof(int));
    int*   goff    = (int*)alloc((NG + 1) * sizeof(int));
    float* sc1 = (float*)alloc(DH * 4); float* sh1 = (float*)alloc(DH * 4);
    float* sc2 = (float*)alloc(DH * 4); float* sh2 = (float*)alloc(DH * 4);
    float* sc3 = (float*)alloc(DH * 4); float* sh3 = (float*)alloc(DH * 4);

    const int layerBlocks = (NN + 63) / 64;          // 782
    const int cvtBlocks   = (NN * DH / 8 + 255) / 256;

    // ---- zero all stats slots once
    hipMemsetAsync(statsAll, 0, 3 * NSLOT * 256 * sizeof(float), stream);

    // ---- CSR build: coarse scatter -> bucket scan -> bucket finalize
    hipMemsetAsync(bukCnt, 0, NBUK * sizeof(int), stream);
    coarse_scatter_kernel<<<CSB, 256, 0, stream>>>(srcp, dstp, bukCnt, pairs);
    bukscan_kernel<<<1, 256, 0, stream>>>(bukCnt, bukBase);
    bucket_finalize_kernel<<<NBUK, 256, 0, stream>>>(pairs, bukCnt, bukBase, offsets, csr_src);

    // ---- graph ranges for pooling (batch sorted -> binary search)
    goff_kernel<<<(NG + 256) / 256, 256, 0, stream>>>(batch, goff);

    // ---- dtype prep
    convert_x_kernel<<<cvtBlocks, 256, 0, stream>>>(x, xb);
    transpose_w_kernel<<<96, 256, 0, stream>>>(wr1, wl1, wr2, wl2, wr3, wl3,
                                               wrt1, wlt1, wrt2, wlt2, wrt3, wlt3);

    // ---- layer 1
    layer_kernel<false><<<layerBlocks, 256, 0, stream>>>(xb, wrt1, wlt1, b1, nullptr, nullptr, offsets, csr_src, hAb, stats1);
    finalize_kernel<<<1, 128, 0, stream>>>(stats1, g1, be1, sc1, sh1);

    // ---- layer 2
    layer_kernel<true><<<layerBlocks, 256, 0, stream>>>(hAb, wrt2, wlt2, b2, sc1, sh1, offsets, csr_src, hBb, stats2);
    finalize_kernel<<<1, 128, 0, stream>>>(stats2, g2, be2, sc2, sh2);

    // ---- layer 3
    layer_kernel<true><<<layerBlocks, 256, 0, stream>>>(hBb, wrt3, wlt3, b3, sc2, sh2, offsets, csr_src, hAb, stats3);
    finalize_kernel<<<1, 128, 0, stream>>>(stats3, g3, be3, sc3, sh3);

    // ---- pool + classify (fused)
    pool_classify_kernel<<<NG, 128, 0, stream>>>(hAb, goff, sc3, sh3, wcls, bcls, out);
}

// Round 16
// 225.488 us; speedup vs baseline: 1.3127x; 1.3127x over previous
//
#include <hip/hip_runtime.h>

// GNN: 3x (GraphConv -> BatchNorm -> ReLU) -> global_mean_pool -> Linear.
// bf16 MFMA pipeline: features bf16, mfma_f32_16x16x32_bf16, fp32 acc/stats.
//
// r15: REVERT r14's agg+gemm fusion (53KB LDS dropped gather occupancy
// 45%->19%, 80us vs 44+12 separate: latency-bound gathers need TLP, not
// fusion). Keep r14's collapsed CSR build (3 kernels) and fold goff binary
// search into pool_classify. Structure = r12 (260us best) + launch savings.
//
// History: r1 CSR vs 1.3ms scatter atomics; r5 global_load_lds divergent-src
// 65x HBM amp; r4-r8 fp32 FMA plateau (LDS-feed wall); r9 bf16 MFMA (363);
// r10 XCD-local 2-level sort (322); r11 barrier-free gemm (314); r12 stats
// 32-slot spread + fusions (260); r13 col-slicing regressed (283, L2 thrash
// regardless of slicing -- block->XCD mapping not round-robin); r14 fusion
// regressed (296). Gather ~103MB/layer at ~2.9TB/s is the structural floor.

constexpr int   NN   = 50000;
constexpr int   NE   = 800000;
constexpr int   DH   = 128;
constexpr int   NC   = 10;
constexpr int   NG   = 1024;
constexpr float EPSV = 1e-5f;
constexpr int   NBUK = (NN + 255) / 256;    // 196 coarse buckets (dst>>8)
constexpr int   BCAP = 5120;                // slots per bucket (avg 4081, 16 sigma)
constexpr int   EPB  = 8192;                // edges per coarse block
constexpr int   CSB  = (NE + EPB - 1) / EPB; // 98 coarse blocks
constexpr int   NSLOT= 32;                  // stats atomic spread factor

typedef __attribute__((ext_vector_type(8))) short bf16x8;
typedef __attribute__((ext_vector_type(4))) float f32x4;

__device__ __forceinline__ float bflo(unsigned u) { return __uint_as_float(u << 16); }
__device__ __forceinline__ float bfhi(unsigned u) { return __uint_as_float(u & 0xffff0000u); }
__device__ __forceinline__ unsigned short f2bf(float f) {
    unsigned u = __float_as_uint(f);
    return (unsigned short)((u + 0x7fffu + ((u >> 16) & 1u)) >> 16);
}
__device__ __forceinline__ unsigned pk2(float a, float b) {
    return (unsigned)f2bf(a) | ((unsigned)f2bf(b) << 16);
}

// ------------------------------------------------- CSR build (2-level sort) ---
__global__ __launch_bounds__(256) void coarse_scatter_kernel(
    const int* __restrict__ src, const int* __restrict__ dst,
    int* __restrict__ bukCnt, int2* __restrict__ pairs)
{
    __shared__ int cnt[NBUK], base[NBUK], cur[NBUK];
    const int tid = threadIdx.x;
    const int e0 = blockIdx.x * EPB;
    const int n  = min(EPB, NE - e0);

    for (int b = tid; b < NBUK; b += 256) cnt[b] = 0;
    __syncthreads();
    for (int i = tid; i < n; i += 256)
        atomicAdd(&cnt[dst[e0 + i] >> 8], 1);
    __syncthreads();
    for (int b = tid; b < NBUK; b += 256) {
        base[b] = (cnt[b] > 0) ? atomicAdd(&bukCnt[b], cnt[b]) : 0;
        cur[b] = 0;
    }
    __syncthreads();
    for (int i = tid; i < n; i += 256) {
        int d = dst[e0 + i], s = src[e0 + i];
        int b = d >> 8;
        int r = atomicAdd(&cur[b], 1);
        int p = base[b] + r;
        if (p >= BCAP) p = BCAP - 1;
        pairs[(size_t)b * BCAP + p] = make_int2(s, d);
    }
}

__global__ __launch_bounds__(256) void bukscan_kernel(
    const int* __restrict__ bukCnt, int* __restrict__ bukBase)
{
    __shared__ int tmp[256];
    int t = threadIdx.x;
    int v = (t < NBUK) ? bukCnt[t] : 0;
    tmp[t] = v;
    __syncthreads();
    for (int off = 1; off < 256; off <<= 1) {
        int u = (t >= off) ? tmp[t - off] : 0;
        __syncthreads();
        tmp[t] += u;
        __syncthreads();
    }
    if (t < NBUK) bukBase[t] = tmp[t] - v;   // exclusive
}

// Per-bucket: degree count -> local prefix -> offsets -> fine scatter.
__global__ __launch_bounds__(256) void bucket_finalize_kernel(
    const int2* __restrict__ pairs, const int* __restrict__ bukCnt,
    const int* __restrict__ bukBase, int* __restrict__ offsets,
    int* __restrict__ csr_src)
{
    __shared__ int cnt[256], tmp[256], pos[256];
    const int b = blockIdx.x;
    const int tid = threadIdx.x;
    cnt[tid] = 0;
    __syncthreads();
    const int n = min(bukCnt[b], BCAP);
    const int2* p = pairs + (size_t)b * BCAP;
    for (int i = tid; i < n; i += 256)
        atomicAdd(&cnt[p[i].y & 255], 1);
    __syncthreads();
    int d = cnt[tid];
    tmp[tid] = d;
    __syncthreads();
    for (int off = 1; off < 256; off <<= 1) {
        int u = (tid >= off) ? tmp[tid - off] : 0;
        __syncthreads();
        tmp[tid] += u;
        __syncthreads();
    }
    const int base = bukBase[b];
    int o = base + tmp[tid] - d;
    pos[tid] = o;
    int node = b * 256 + tid;
    if (node < NN) offsets[node] = o;
    if (b == NBUK - 1 && tid == 0) offsets[NN] = NE;
    __syncthreads();
    for (int i = tid; i < n; i += 256) {
        int2 e = p[i];
        int r = atomicAdd(&pos[e.y & 255], 1);
        csr_src[r] = e.x;
    }
}

// ------------------------------------------------------------ conversions ---
__global__ __launch_bounds__(256) void convert_x_kernel(
    const float* __restrict__ x, unsigned short* __restrict__ xb)
{
    int i = blockIdx.x * 256 + threadIdx.x;   // elem8 index
    if (i >= NN * DH / 8) return;
    const float4* p = reinterpret_cast<const float4*>(x + (size_t)i * 8);
    float4 v0 = p[0], v1 = p[1];
    uint4 o;
    o.x = pk2(v0.x, v0.y); o.y = pk2(v0.z, v0.w);
    o.z = pk2(v1.x, v1.y); o.w = pk2(v1.z, v1.w);
    *reinterpret_cast<uint4*>(xb + (size_t)i * 8) = o;
}

__global__ __launch_bounds__(256) void transpose_w_kernel(
    const float* __restrict__ w0, const float* __restrict__ w1,
    const float* __restrict__ w2, const float* __restrict__ w3,
    const float* __restrict__ w4, const float* __restrict__ w5,
    unsigned short* __restrict__ t0, unsigned short* __restrict__ t1,
    unsigned short* __restrict__ t2, unsigned short* __restrict__ t3,
    unsigned short* __restrict__ t4, unsigned short* __restrict__ t5)
{
    const float* srcs[6] = {w0, w1, w2, w3, w4, w5};
    unsigned short* dsts[6] = {t0, t1, t2, t3, t4, t5};
    int m = blockIdx.x >> 4;
    int sub = blockIdx.x & 15;
    const float* s = srcs[m];
    unsigned short* d = dsts[m];
    for (int it = 0; it < 4; ++it) {
        int i = sub * 1024 + it * 256 + threadIdx.x;   // 0..16383
        int c = i & 127, k = i >> 7;
        d[c * 128 + k] = f2bf(s[k * 128 + c]);         // coalesced read
    }
}

// -------------------------------------------------------------- aggregate ---
// 16 lanes per node, 8 bf16 cols per lane; fp32 accumulate; TRANSFORM applies
// prev layer's BN+ReLU per gathered element. Zero LDS -> full occupancy for
// latency-bound gathers (r14 lesson: fusion with LDS-heavy gemm kills TLP).
template <bool TRANSFORM>
__global__ __launch_bounds__(256) void aggregate_kernel(
    const unsigned short* __restrict__ xb, const int* __restrict__ offsets,
    const int* __restrict__ csr_src, const float* __restrict__ sc,
    const float* __restrict__ sh, unsigned short* __restrict__ aggb)
{
    int tid = blockIdx.x * 256 + threadIdx.x;
    int node = tid >> 4;
    if (node >= NN) return;
    int c8 = (tid & 15) * 8;

    float scv[8], shv[8];
    if (TRANSFORM) {
        float4 a = *reinterpret_cast<const float4*>(sc + c8);
        float4 b = *reinterpret_cast<const float4*>(sc + c8 + 4);
        scv[0]=a.x; scv[1]=a.y; scv[2]=a.z; scv[3]=a.w;
        scv[4]=b.x; scv[5]=b.y; scv[6]=b.z; scv[7]=b.w;
        float4 c = *reinterpret_cast<const float4*>(sh + c8);
        float4 d = *reinterpret_cast<const float4*>(sh + c8 + 4);
        shv[0]=c.x; shv[1]=c.y; shv[2]=c.z; shv[3]=c.w;
        shv[4]=d.x; shv[5]=d.y; shv[6]=d.z; shv[7]=d.w;
    }

    float acc[8] = {0.f,0.f,0.f,0.f,0.f,0.f,0.f,0.f};
    auto addv = [&](uint4 v) {
        float f[8] = {bflo(v.x), bfhi(v.x), bflo(v.y), bfhi(v.y),
                      bflo(v.z), bfhi(v.z), bflo(v.w), bfhi(v.w)};
#pragma unroll
        for (int j = 0; j < 8; ++j) {
            float t = TRANSFORM ? fmaxf(fmaf(f[j], scv[j], shv[j]), 0.f) : f[j];
            acc[j] += t;
        }
    };

    int beg = offsets[node], end = offsets[node + 1];
    int e = beg;
    for (; e + 3 < end; e += 4) {        // 4 gathers in flight
        int s0 = csr_src[e],     s1 = csr_src[e + 1];
        int s2 = csr_src[e + 2], s3 = csr_src[e + 3];
        uint4 v0 = *reinterpret_cast<const uint4*>(xb + (size_t)s0 * DH + c8);
        uint4 v1 = *reinterpret_cast<const uint4*>(xb + (size_t)s1 * DH + c8);
        uint4 v2 = *reinterpret_cast<const uint4*>(xb + (size_t)s2 * DH + c8);
        uint4 v3 = *reinterpret_cast<const uint4*>(xb + (size_t)s3 * DH + c8);
        addv(v0); addv(v1); addv(v2); addv(v3);
    }
    for (; e < end; ++e)
        addv(*reinterpret_cast<const uint4*>(xb + (size_t)csr_src[e] * DH + c8));

    uint4 o;
    o.x = pk2(acc[0], acc[1]); o.y = pk2(acc[2], acc[3]);
    o.z = pk2(acc[4], acc[5]); o.w = pk2(acc[6], acc[7]);
    *reinterpret_cast<uint4*>(aggb + (size_t)node * DH + c8) = o;
}

// ------------------------------------------------------------- gemm mfma ---
// OUT = t(X) @ Wr + A @ Wl + bias.  64 rows/block, 4 waves x 16 rows.
// Barrier-free K-loop (A frags direct from global, mfma A-layout == one
// uint4/lane); W^T one matrix at a time in LDS (34.8KB -> 4 blocks/CU).
// Stats -> slot blockIdx&31 (r12: L2 atomic serialization fix).
template <bool TRANSFORM>
__global__ __launch_bounds__(256, 4) void gemm_mfma_kernel(
    const unsigned short* __restrict__ Xb, const unsigned short* __restrict__ Ab,
    const unsigned short* __restrict__ Wrt, const unsigned short* __restrict__ Wlt,
    const float* __restrict__ bias, const float* __restrict__ scIn,
    const float* __restrict__ shIn, unsigned short* __restrict__ OUTb,
    float* __restrict__ stats)
{
    __shared__ unsigned short sW[128][136];   // 34.8 KB, Wr then Wl
    __shared__ float sScale[DH], sShift[DH];

    const int tid  = threadIdx.x;
    const int lane = tid & 63;
    const int wave = tid >> 6;
    const int row0 = blockIdx.x * 64;
    const int wrow = wave * 16;
    const int l15  = lane & 15;
    const int lk   = (lane >> 4) * 8;    // k sub-offset for A/B frags

    if (TRANSFORM && tid < DH) {
        sScale[tid] = scIn[tid];
        sShift[tid] = shIn[tid];
    }
    // stage Wr^T
#pragma unroll
    for (int i = 0; i < 8; ++i) {
        int f = i * 256 + tid;        // 0..2047
        int c = f >> 4;
        int ks = (f & 15) * 8;
        *reinterpret_cast<uint4*>(&sW[c][ks]) =
            *reinterpret_cast<const uint4*>(Wrt + c * 128 + ks);
    }

    f32x4 acc[8];
#pragma unroll
    for (int nt = 0; nt < 8; ++nt) acc[nt] = (f32x4){0.f, 0.f, 0.f, 0.f};

    const int arow = row0 + wrow + l15;          // this lane's A row
    const bool valid = arow < NN;
    const unsigned short* xptr = Xb + (size_t)arow * DH + lk;
    const unsigned short* aptr = Ab + (size_t)arow * DH + lk;

    uint4 pre[4];
#pragma unroll
    for (int t = 0; t < 4; ++t)
        pre[t] = valid ? *reinterpret_cast<const uint4*>(xptr + t * 32)
                       : make_uint4(0u, 0u, 0u, 0u);

    __syncthreads();   // Wr ready

    // ---- phase 1: t(X) @ Wr
#pragma unroll
    for (int t = 0; t < 4; ++t) {
        uint4 v = pre[t];
        if (TRANSFORM) {
            int cb = t * 32 + lk;
            float f[8] = {bflo(v.x), bfhi(v.x), bflo(v.y), bfhi(v.y),
                          bflo(v.z), bfhi(v.z), bflo(v.w), bfhi(v.w)};
#pragma unroll
            for (int j = 0; j < 8; ++j)
                f[j] = fmaxf(fmaf(f[j], sScale[cb + j], sShift[cb + j]), 0.f);
            v.x = pk2(f[0], f[1]); v.y = pk2(f[2], f[3]);
            v.z = pk2(f[4], f[5]); v.w = pk2(f[6], f[7]);
        }
        bf16x8 a = *reinterpret_cast<bf16x8*>(&v);
        const int kb = t * 32;
#pragma unroll
        for (int nt = 0; nt < 8; ++nt) {
            bf16x8 b = *reinterpret_cast<const bf16x8*>(&sW[nt * 16 + l15][kb + lk]);
            acc[nt] = __builtin_amdgcn_mfma_f32_16x16x32_bf16(a, b, acc[nt], 0, 0, 0);
        }
    }

    // prefetch agg fragments while waves drain phase 1
#pragma unroll
    for (int t = 0; t < 4; ++t)
        pre[t] = valid ? *reinterpret_cast<const uint4*>(aptr + t * 32)
                       : make_uint4(0u, 0u, 0u, 0u);

    __syncthreads();   // all waves done reading Wr
    // stage Wl^T
#pragma unroll
    for (int i = 0; i < 8; ++i) {
        int f = i * 256 + tid;
        int c = f >> 4;
        int ks = (f & 15) * 8;
        *reinterpret_cast<uint4*>(&sW[c][ks]) =
            *reinterpret_cast<const uint4*>(Wlt + c * 128 + ks);
    }
    __syncthreads();   // Wl ready

    // ---- phase 2: A @ Wl
#pragma unroll
    for (int t = 0; t < 4; ++t) {
        uint4 v = pre[t];
        bf16x8 a = *reinterpret_cast<bf16x8*>(&v);
        const int kb = t * 32;
#pragma unroll
        for (int nt = 0; nt < 8; ++nt) {
            bf16x8 b = *reinterpret_cast<const bf16x8*>(&sW[nt * 16 + l15][kb + lk]);
            acc[nt] = __builtin_amdgcn_mfma_f32_16x16x32_bf16(a, b, acc[nt], 0, 0, 0);
        }
    }

    // ---- epilogue: bias, bf16 store, fp32 column stats
    float s_[8] = {0,0,0,0,0,0,0,0}, q_[8] = {0,0,0,0,0,0,0,0};
#pragma unroll
    for (int nt = 0; nt < 8; ++nt) {
        float bvn = bias[nt * 16 + l15];
#pragma unroll
        for (int r = 0; r < 4; ++r) {
            int orow = row0 + wrow + ((lane >> 4) << 2) + r;
            float o = acc[nt][r] + bvn;
            if (orow < NN) {
                OUTb[(size_t)orow * DH + nt * 16 + l15] = f2bf(o);
                s_[nt] += o;
                q_[nt] += o * o;
            }
        }
    }
#pragma unroll
    for (int nt = 0; nt < 8; ++nt) {
        s_[nt] += __shfl_xor(s_[nt], 16, 64);
        s_[nt] += __shfl_xor(s_[nt], 32, 64);
        q_[nt] += __shfl_xor(q_[nt], 16, 64);
        q_[nt] += __shfl_xor(q_[nt], 32, 64);
    }
    __syncthreads();                     // sW now dead -> reuse as scratch
    float* ldsS = reinterpret_cast<float*>(&sW[0][0]);   // [4][128]
    float* ldsQ = ldsS + 512;                            // [4][128]
    if (lane < 16) {
#pragma unroll
        for (int nt = 0; nt < 8; ++nt) {
            ldsS[wave * DH + nt * 16 + l15] = s_[nt];
            ldsQ[wave * DH + nt * 16 + l15] = q_[nt];
        }
    }
    __syncthreads();
    if (tid < DH) {
        float s = ldsS[tid] + ldsS[DH + tid] + ldsS[2 * DH + tid] + ldsS[3 * DH + tid];
        float q = ldsQ[tid] + ldsQ[DH + tid] + ldsQ[2 * DH + tid] + ldsQ[3 * DH + tid];
        float* slot = stats + (size_t)(blockIdx.x & (NSLOT - 1)) * 256;
        atomicAdd(&slot[tid], s);
        atomicAdd(&slot[128 + tid], q);
    }
}

// --------------------------------------------------------------- finalize ---
__global__ __launch_bounds__(128) void finalize_kernel(
    const float* __restrict__ stats, const float* __restrict__ gamma,
    const float* __restrict__ beta, float* __restrict__ sc,
    float* __restrict__ sh)
{
    int j = threadIdx.x;
    float s = 0.f, q = 0.f;
#pragma unroll 8
    for (int sl = 0; sl < NSLOT; ++sl) {
        s += stats[sl * 256 + j];
        q += stats[sl * 256 + 128 + j];
    }
    float mean = s * (1.f / NN);
    float var  = q * (1.f / NN) - mean * mean;
    float sf = rsqrtf(var + EPSV) * gamma[j];
    sc[j] = sf;
    sh[j] = beta[j] - mean * sf;
}

// ---------------------------------------------------------- pool+classify ---
// Inline binary search for goff (batch sorted); BN3 applied lazily; head GEMV.
__global__ __launch_bounds__(128) void pool_classify_kernel(
    const unsigned short* __restrict__ Hb, const int* __restrict__ batch,
    const float* __restrict__ sc, const float* __restrict__ sh,
    const float* __restrict__ wcls, const float* __restrict__ bcls,
    float* __restrict__ out)
{
    __shared__ float pl[DH];
    __shared__ int bnd[2];
    int g = blockIdx.x;
    int j = threadIdx.x;
    if (j < 2) {
        int target = g + j;
        int lo = 0, hi = NN;
        while (lo < hi) {
            int mid = (lo + hi) >> 1;
            if (batch[mid] < target) lo = mid + 1; else hi = mid;
        }
        bnd[j] = lo;
    }
    __syncthreads();
    int beg = bnd[0], end = bnd[1];
    float s = 0.f;
    for (int n = beg; n < end; ++n)
        s += bflo((unsigned)Hb[(size_t)n * DH + j]);
    float cnt = (float)(end - beg);
    pl[j] = (s * sc[j] + cnt * sh[j]) / fmaxf(cnt, 1.f);
    __syncthreads();
    if (j < NC) {
        float v = bcls[j];
#pragma unroll 16
        for (int k = 0; k < DH; ++k) v += pl[k] * wcls[k * NC + j];
        out[(size_t)g * NC + j] = v;
    }
}

// ----------------------------------------------------------------- launch ---
extern "C" void kernel_launch(void* const* d_in, const int* in_sizes, int n_in,
                              void* d_out, int out_size, void* d_ws, size_t ws_size,
                              hipStream_t stream)
{
    const float* x    = (const float*)d_in[0];
    const int*   ei   = (const int*)d_in[1];
    const int*   batch= (const int*)d_in[2];
    const float* wr1  = (const float*)d_in[3];
    const float* wl1  = (const float*)d_in[4];
    const float* b1   = (const float*)d_in[5];
    const float* wr2  = (const float*)d_in[6];
    const float* wl2  = (const float*)d_in[7];
    const float* b2   = (const float*)d_in[8];
    const float* wr3  = (const float*)d_in[9];
    const float* wl3  = (const float*)d_in[10];
    const float* b3   = (const float*)d_in[11];
    const float* g1   = (const float*)d_in[12];
    const float* be1  = (const float*)d_in[13];
    const float* g2   = (const float*)d_in[14];
    const float* be2  = (const float*)d_in[15];
    const float* g3   = (const float*)d_in[16];
    const float* be3  = (const float*)d_in[17];
    const float* wcls = (const float*)d_in[18];
    const float* bcls = (const float*)d_in[19];
    float* out = (float*)d_out;

    const int* srcp = ei;
    const int* dstp = ei + NE;

    char* ws = (char*)d_ws;
    const size_t featB16 = (size_t)NN * DH * sizeof(unsigned short);   // 12.8 MB
    size_t off = 0;
    auto alloc = [&](size_t bytes) {
        void* p = ws + off;
        off += (bytes + 255) & ~(size_t)255;
        return p;
    };
    unsigned short* xb    = (unsigned short*)alloc(featB16);
    unsigned short* aggb  = (unsigned short*)alloc(featB16);
    unsigned short* hAb   = (unsigned short*)alloc(featB16);
    unsigned short* hBb   = (unsigned short*)alloc(featB16);
    unsigned short* wrt1  = (unsigned short*)alloc(DH * DH * 2);
    unsigned short* wlt1  = (unsigned short*)alloc(DH * DH * 2);
    unsigned short* wrt2  = (unsigned short*)alloc(DH * DH * 2);
    unsigned short* wlt2  = (unsigned short*)alloc(DH * DH * 2);
    unsigned short* wrt3  = (unsigned short*)alloc(DH * DH * 2);
    unsigned short* wlt3  = (unsigned short*)alloc(DH * DH * 2);
    float* statsAll = (float*)alloc(3 * NSLOT * 256 * sizeof(float));  // 96 KB
    float* stats1 = statsAll;
    float* stats2 = statsAll + NSLOT * 256;
    float* stats3 = statsAll + 2 * NSLOT * 256;
    int*   offsets = (int*)alloc((NN + 1) * sizeof(int));
    int*   csr_src = (int*)alloc(NE * sizeof(int));
    int2*  pairs   = (int2*)alloc((size_t)NBUK * BCAP * sizeof(int2));  // 8 MB
    int*   bukCnt  = (int*)alloc(NBUK * sizeof(int));
    int*   bukBase = (int*)alloc(NBUK * sizeof(int));
    float* sc1 = (float*)alloc(DH * 4); float* sh1 = (float*)alloc(DH * 4);
    float* sc2 = (float*)alloc(DH * 4); float* sh2 = (float*)alloc(DH * 4);
    float* sc3 = (float*)alloc(DH * 4); float* sh3 = (float*)alloc(DH * 4);

    const int aggBlocks  = (NN * 16 + 255) / 256;   // 3125
    const int gemmBlocks = (NN + 63) / 64;          // 782
    const int cvtBlocks  = (NN * DH / 8 + 255) / 256;

    // ---- zero all stats slots once
    hipMemsetAsync(statsAll, 0, 3 * NSLOT * 256 * sizeof(float), stream);

    // ---- CSR build: coarse scatter -> bucket scan -> bucket finalize
    hipMemsetAsync(bukCnt, 0, NBUK * sizeof(int), stream);
    coarse_scatter_kernel<<<CSB, 256, 0, stream>>>(srcp, dstp, bukCnt, pairs);
    bukscan_kernel<<<1, 256, 0, stream>>>(bukCnt, bukBase);
    bucket_finalize_kernel<<<NBUK, 256, 0, stream>>>(pairs, bukCnt, bukBase, offsets, csr_src);

    // ---- dtype prep
    convert_x_kernel<<<cvtBlocks, 256, 0, stream>>>(x, xb);
    transpose_w_kernel<<<96, 256, 0, stream>>>(wr1, wl1, wr2, wl2, wr3, wl3,
                                               wrt1, wlt1, wrt2, wlt2, wrt3, wlt3);

    // ---- layer 1
    aggregate_kernel<false><<<aggBlocks, 256, 0, stream>>>(xb, offsets, csr_src, nullptr, nullptr, aggb);
    gemm_mfma_kernel<false><<<gemmBlocks, 256, 0, stream>>>(xb, aggb, wrt1, wlt1, b1, nullptr, nullptr, hAb, stats1);
    finalize_kernel<<<1, 128, 0, stream>>>(stats1, g1, be1, sc1, sh1);

    // ---- layer 2
    aggregate_kernel<true><<<aggBlocks, 256, 0, stream>>>(hAb, offsets, csr_src, sc1, sh1, aggb);
    gemm_mfma_kernel<true><<<gemmBlocks, 256, 0, stream>>>(hAb, aggb, wrt2, wlt2, b2, sc1, sh1, hBb, stats2);
    finalize_kernel<<<1, 128, 0, stream>>>(stats2, g2, be2, sc2, sh2);

    // ---- layer 3
    aggregate_kernel<true><<<aggBlocks, 256, 0, stream>>>(hBb, offsets, csr_src, sc2, sh2, aggb);
    gemm_mfma_kernel<true><<<gemmBlocks, 256, 0, stream>>>(hBb, aggb, wrt3, wlt3, b3, sc2, sh2, hAb, stats3);
    finalize_kernel<<<1, 128, 0, stream>>>(stats3, g3, be3, sc3, sh3);

    // ---- pool + classify (fused, inline goff binary search)
    pool_classify_kernel<<<NG, 128, 0, stream>>>(hAb, batch, sc3, sh3, wcls, bcls, out);
}